// Round 6
// baseline (1364.808 us; speedup 1.0000x reference)
//
#include <hip/hip_runtime.h>
#include <hip/hip_bf16.h>

#define N_NODES 100000
#define N_EDGES 1600000
#define F 128
#define KW 272          // sage padded K: 17 frags x 16
#define KS 144          // zs padded K: 128 + bias -> 9 frags
#define KD 128          // zd K: 8 frags
#define EROUNDS 8       // edge kernel: 16 edges/slot-round, 128 edges/block
#define NBUCK 512       // CSR buckets (dst>>8), 256 nodes each
#define BCAP 5120       // bucket capacity: full-bucket mean 4096 (256 nodes x deg 16), sd 64 -> +16 sigma
#define NB 98           // scan blocks: ceil(100000/1024)

typedef short bf16x8 __attribute__((ext_vector_type(8)));
typedef float f32x16 __attribute__((ext_vector_type(16)));
typedef _Float16 half8 __attribute__((ext_vector_type(8)));
typedef _Float16 half4 __attribute__((ext_vector_type(4)));

__device__ __forceinline__ short f2bf(float x) {
    unsigned u = __builtin_bit_cast(unsigned, x);
    u += 0x7FFF + ((u >> 16) & 1);          // RNE
    return (short)(u >> 16);
}
__device__ __forceinline__ float bflo(unsigned u) {
    return __builtin_bit_cast(float, u << 16);
}
__device__ __forceinline__ float bfhi(unsigned u) {
    return __builtin_bit_cast(float, u & 0xFFFF0000u);
}

// ---------------- bucketed CSR build ----------------
// Phase 1: scatter (dst,src) into 512 dst-range buckets; dense per-bucket regions.
__global__ void bucket_scatter(const int* __restrict__ src, const int* __restrict__ dst,
                               int* __restrict__ bcur, uint2* __restrict__ bstore) {
    int i = blockIdx.x * 256 + threadIdx.x;
    int d = dst[i], s = src[i];
    int bk = d >> 8;
    int p = atomicAdd(&bcur[bk], 1);
    if (p < BCAP) bstore[(size_t)bk * BCAP + p] = make_uint2((unsigned)d, (unsigned)s);
}

// Phase 2: per-bucket degree count via LDS atomics, coalesced deg write.
__global__ __launch_bounds__(256) void bucket_deg(const uint2* __restrict__ bstore,
                                                  const int* __restrict__ bcur,
                                                  int* __restrict__ deg) {
    __shared__ int cnt[256];
    int b = blockIdx.x, t = threadIdx.x;
    cnt[t] = 0;
    __syncthreads();
    int n = bcur[b]; if (n > BCAP) n = BCAP;
    const uint2* p = bstore + (size_t)b * BCAP;
    for (int i = t; i < n; i += 256) atomicAdd(&cnt[p[i].x & 255], 1);
    __syncthreads();
    int node = b * 256 + t;
    if (node < N_NODES) deg[node] = cnt[t];
}

// Multi-block scan: K1 per-block inclusive scans + block sums
__global__ __launch_bounds__(1024) void scan1_kernel(const int* __restrict__ deg,
                                                     int* __restrict__ incl,
                                                     int* __restrict__ bsum) {
    __shared__ int wsum[16];
    int t = threadIdx.x, lane = t & 63, wid = t >> 6;
    int i = blockIdx.x * 1024 + t;
    int v = (i < N_NODES) ? deg[i] : 0;
    int sc = v;
#pragma unroll
    for (int off = 1; off < 64; off <<= 1) {
        int u = __shfl_up(sc, off, 64);
        if (lane >= off) sc += u;
    }
    if (lane == 63) wsum[wid] = sc;
    __syncthreads();
    if (wid == 0) {
        int wv = (lane < 16) ? wsum[lane] : 0;
        int wi = wv;
#pragma unroll
        for (int off = 1; off < 16; off <<= 1) {
            int u = __shfl_up(wi, off, 64);
            if (lane >= off) wi += u;
        }
        if (lane < 16) wsum[lane] = wi - wv;
    }
    __syncthreads();
    int full = sc + wsum[wid];
    if (i < N_NODES) incl[i] = full;
    if (t == 1023) bsum[blockIdx.x] = full;
}

// K2: scan the 98 block sums (exclusive), write grand total to row_ptr[N]
__global__ void scan2_kernel(const int* __restrict__ bsum, int* __restrict__ boff,
                             int* __restrict__ row_ptr) {
    __shared__ int w0;
    int t = threadIdx.x, lane = t & 63, wid = t >> 6;
    int v = (t < NB) ? bsum[t] : 0;
    int sc = v;
#pragma unroll
    for (int off = 1; off < 64; off <<= 1) {
        int u = __shfl_up(sc, off, 64);
        if (lane >= off) sc += u;
    }
    if (wid == 0 && lane == 63) w0 = sc;
    __syncthreads();
    if (wid == 1) sc += w0;
    if (t < NB) boff[t] = sc - v;
    if (t == NB - 1) row_ptr[N_NODES] = sc;
}

// K3: exclusive row_ptr + inv_deg
__global__ __launch_bounds__(1024) void scan3_kernel(const int* __restrict__ incl,
                                                     const int* __restrict__ deg,
                                                     const int* __restrict__ boff,
                                                     int* __restrict__ row_ptr,
                                                     float* __restrict__ invd) {
    int i = blockIdx.x * 1024 + threadIdx.x;
    if (i >= N_NODES) return;
    int d = deg[i];
    row_ptr[i] = incl[i] - d + boff[blockIdx.x];
    invd[i] = 1.0f / (float)(d > 1 ? d : 1);
}

// Phase 3: per-bucket CSR fill; LDS cursors, writes land in a ~16KB L2 window.
__global__ __launch_bounds__(256) void bucket_fill(const uint2* __restrict__ bstore,
                                                   const int* __restrict__ bcur,
                                                   const int* __restrict__ row_ptr,
                                                   int* __restrict__ csr_src) {
    __shared__ int cur[256];
    int b = blockIdx.x, t = threadIdx.x;
    int node = b * 256 + t;
    cur[t] = (node < N_NODES) ? row_ptr[node] : 0;
    __syncthreads();
    int n = bcur[b]; if (n > BCAP) n = BCAP;
    const uint2* p = bstore + (size_t)b * BCAP;
    for (int i = t; i < n; i += 256) {
        uint2 e = p[i];
        int slot = atomicAdd(&cur[e.x & 255], 1);
        csr_src[slot] = (int)e.y;
    }
}

// ---------------- fp32 -> bf16 convert ----------------

__global__ void convert_bf16_kernel(const float* __restrict__ in, ushort* __restrict__ out) {
    int idx = (blockIdx.x * 256 + threadIdx.x) * 8;
    float4 a = *(const float4*)&in[idx];
    float4 b = *(const float4*)&in[idx + 4];
    ushort o[8];
    o[0] = (ushort)f2bf(a.x); o[1] = (ushort)f2bf(a.y);
    o[2] = (ushort)f2bf(a.z); o[3] = (ushort)f2bf(a.w);
    o[4] = (ushort)f2bf(b.x); o[5] = (ushort)f2bf(b.y);
    o[6] = (ushort)f2bf(b.z); o[7] = (ushort)f2bf(b.w);
    *(uint4*)&out[idx] = *(uint4*)o;
}

// ---------------- weight prep ----------------

__global__ void prep_sage_w(const float* __restrict__ wsx, const float* __restrict__ wnx,
                            const float* __restrict__ b, ushort* __restrict__ aw) {
    int idx = blockIdx.x * 256 + threadIdx.x;
    if (idx >= 128 * KW) return;
    int h = idx / KW;
    int k = idx - h * KW;
    float v = 0.f;
    if (k < 128) v = wsx[(size_t)k * 128 + h];
    else if (k < 256) v = wnx[(size_t)(k - 128) * 128 + h];
    else if (k == 256) v = b[h];
    aw[idx] = (ushort)f2bf(v);
}

__global__ void prep_zs_w(const float* __restrict__ mw1, const float* __restrict__ mb1,
                          ushort* __restrict__ aw) {
    int idx = blockIdx.x * 256 + threadIdx.x;
    if (idx >= 128 * KS) return;
    int h = idx / KS;
    int k = idx - h * KS;
    float v = 0.f;
    if (k < 128) v = mw1[(size_t)k * 128 + h];
    else if (k == 128) v = mb1[h];
    aw[idx] = (ushort)f2bf(v);
}

__global__ void prep_zd_w(const float* __restrict__ mw1, ushort* __restrict__ aw) {
    int idx = blockIdx.x * 256 + threadIdx.x;
    if (idx >= 128 * KD) return;
    int h = idx / KD;
    int k = idx - h * KD;
    aw[idx] = (ushort)f2bf(mw1[(size_t)(128 + k) * 128 + h]);
}

// ---------------- fused agg + SAGE layer (32 nodes/block) ----------------
// Phase 1: 4 waves aggregate 8 nodes each into LDS (bf16, stride 136 ushorts).
// Phase 2: weight-stationary MFMA; self term from global, mean term from LDS.
__global__ __launch_bounds__(256) void agg_sage_fused(
    const ushort* __restrict__ hb, const int* __restrict__ csr_src,
    const int* __restrict__ row_ptr, const float* __restrict__ inv_deg,
    const ushort* __restrict__ aw, ushort* __restrict__ hout) {
    __shared__ ushort sM[32 * 136];   // stride 68 dwords: agg writes conflict-free
    int t = threadIdx.x;
    int lane = t & 63, w = t >> 6;
    int l31 = lane & 31, hf = lane >> 5;

    bf16x8 afrag[17];
    const ushort* ap = aw + (size_t)(w * 32 + l31) * KW + hf * 8;
#pragma unroll
    for (int f = 0; f < 17; ++f) afrag[f] = *(const bf16x8*)(ap + f * 16);

    int n0 = blockIdx.x * 32;
    // phase 1: mean aggregation into LDS
    for (int j = 0; j < 8; ++j) {
        int node = n0 + w * 8 + j;
        int s = row_ptr[node], e = row_ptr[node + 1];
        float a0 = 0.f, a1 = 0.f;
        int i = s;
        for (; i + 4 <= e; i += 4) {
            int m0 = csr_src[i], m1 = csr_src[i + 1], m2 = csr_src[i + 2], m3 = csr_src[i + 3];
            unsigned u0 = *(const unsigned*)(hb + (size_t)m0 * F + lane * 2);
            unsigned u1 = *(const unsigned*)(hb + (size_t)m1 * F + lane * 2);
            unsigned u2 = *(const unsigned*)(hb + (size_t)m2 * F + lane * 2);
            unsigned u3 = *(const unsigned*)(hb + (size_t)m3 * F + lane * 2);
            a0 += bflo(u0) + bflo(u1) + bflo(u2) + bflo(u3);
            a1 += bfhi(u0) + bfhi(u1) + bfhi(u2) + bfhi(u3);
        }
        for (; i < e; ++i) {
            int mid = csr_src[i];
            unsigned u = *(const unsigned*)(hb + (size_t)mid * F + lane * 2);
            a0 += bflo(u);
            a1 += bfhi(u);
        }
        float iv = inv_deg[node];
        ushort o[2] = {(ushort)f2bf(a0 * iv), (ushort)f2bf(a1 * iv)};
        *(unsigned*)&sM[(w * 8 + j) * 136 + lane * 2] = *(unsigned*)o;
    }
    __syncthreads();

    // phase 2: MFMA
    int n = n0 + l31;
    const ushort* bs = hb + (size_t)n * F + hf * 8;
    f32x16 acc1, acc2;
#pragma unroll
    for (int r = 0; r < 16; ++r) { acc1[r] = 0.f; acc2[r] = 0.f; }
#pragma unroll
    for (int f = 0; f < 8; ++f) {
        bf16x8 b = *(const bf16x8*)(bs + f * 16);
        acc1 = __builtin_amdgcn_mfma_f32_32x32x16_bf16(afrag[f], b, acc1, 0, 0, 0);
    }
#pragma unroll
    for (int f = 0; f < 8; ++f) {
        bf16x8 b = *(const bf16x8*)&sM[l31 * 136 + hf * 8 + f * 16];
        acc2 = __builtin_amdgcn_mfma_f32_32x32x16_bf16(afrag[8 + f], b, acc2, 0, 0, 0);
    }
    bf16x8 bx;
#pragma unroll
    for (int j = 0; j < 8; ++j) bx[j] = 0;
    if (hf == 0) bx[0] = (short)0x3F80;   // k=256: bias row * 1.0
    acc2 = __builtin_amdgcn_mfma_f32_32x32x16_bf16(afrag[16], bx, acc2, 0, 0, 0);

#pragma unroll
    for (int g = 0; g < 4; ++g) {
        ushort o4[4];
#pragma unroll
        for (int j = 0; j < 4; ++j) {
            float v = acc1[g * 4 + j] + acc2[g * 4 + j];
            v = v > 0.f ? v : 0.01f * v;
            o4[j] = (ushort)f2bf(v);
        }
        *(uint2*)(hout + (size_t)n * F + w * 32 + g * 8 + hf * 4) = *(uint2*)o4;
    }
}

// ---------------- zs/zd precompute via MFMA ----------------
#define STILE 8
__global__ __launch_bounds__(256) void mlp_z_mfma(
    const ushort* __restrict__ hb, const ushort* __restrict__ aws,
    const ushort* __restrict__ awd, _Float16* __restrict__ zs,
    _Float16* __restrict__ zd) {
    int t = threadIdx.x;
    int lane = t & 63, w = t >> 6;
    int l31 = lane & 31, hf = lane >> 5;

    bf16x8 afs[9], afd[8];
    const ushort* aps = aws + (size_t)(w * 32 + l31) * KS + hf * 8;
    const ushort* apd = awd + (size_t)(w * 32 + l31) * KD + hf * 8;
#pragma unroll
    for (int f = 0; f < 9; ++f) afs[f] = *(const bf16x8*)(aps + f * 16);
#pragma unroll
    for (int f = 0; f < 8; ++f) afd[f] = *(const bf16x8*)(apd + f * 16);

    int tile0 = blockIdx.x * STILE;
    for (int tt = 0; tt < STILE; ++tt) {
        int tile = tile0 + tt;
        if (tile >= N_NODES / 32) break;
        int n = tile * 32 + l31;
        const ushort* bp = hb + (size_t)n * F + hf * 8;

        f32x16 accS, accD;
#pragma unroll
        for (int r = 0; r < 16; ++r) { accS[r] = 0.f; accD[r] = 0.f; }
#pragma unroll
        for (int f = 0; f < 8; ++f) {
            bf16x8 b = *(const bf16x8*)(bp + f * 16);
            accS = __builtin_amdgcn_mfma_f32_32x32x16_bf16(afs[f], b, accS, 0, 0, 0);
            accD = __builtin_amdgcn_mfma_f32_32x32x16_bf16(afd[f], b, accD, 0, 0, 0);
        }
        bf16x8 bx;
#pragma unroll
        for (int j = 0; j < 8; ++j) bx[j] = 0;
        if (hf == 0) bx[0] = (short)0x3F80;   // k=128: bias row * 1.0
        accS = __builtin_amdgcn_mfma_f32_32x32x16_bf16(afs[8], bx, accS, 0, 0, 0);

#pragma unroll
        for (int g = 0; g < 4; ++g) {
            half4 os, od;
#pragma unroll
            for (int j = 0; j < 4; ++j) {
                os[j] = (_Float16)accS[g * 4 + j];
                od[j] = (_Float16)accD[g * 4 + j];
            }
            int col = w * 32 + g * 8 + hf * 4;
            *(half4*)(zs + (size_t)n * F + col) = os;
            *(half4*)(zd + (size_t)n * F + col) = od;
        }
    }
}

// ---------------- final edge kernel ----------------
// 16 lanes per edge; ids preloaded for all rounds so gathers issue early.
__global__ __launch_bounds__(256) void edge_final(
    const _Float16* __restrict__ zs, const _Float16* __restrict__ zd,
    const float* __restrict__ ef,
    const int* __restrict__ src, const int* __restrict__ dst,
    const float* __restrict__ mw1, const float* __restrict__ mw2,
    const float* __restrict__ mb2, float* __restrict__ out) {
    int t = threadIdx.x;
    int g = t >> 4;       // edge slot 0..15
    int fl = t & 15;      // feature chunk

    float wf[8], w2a[8], w2b[8];
#pragma unroll
    for (int j = 0; j < 8; ++j) {
        int feat = fl * 8 + j;
        wf[j]  = mw1[(size_t)256 * 128 + feat];
        float2 v = *(const float2*)&mw2[feat * 2];
        w2a[j] = v.x; w2b[j] = v.y;
    }
    float b20 = mb2[0], b21 = mb2[1];

    int e0 = blockIdx.x * (16 * EROUNDS);
    int isv[EROUNDS], idv[EROUNDS];
    float efv[EROUNDS];
#pragma unroll
    for (int r = 0; r < EROUNDS; ++r) {
        int e = e0 + r * 16 + g;
        isv[r] = src[e];
        idv[r] = dst[e];
        efv[r] = ef[e];
    }
#pragma unroll
    for (int r = 0; r < EROUNDS; ++r) {
        int e = e0 + r * 16 + g;
        half8 a = *(const half8*)(zs + (size_t)isv[r] * F + fl * 8);
        half8 b = *(const half8*)(zd + (size_t)idv[r] * F + fl * 8);
        float p0 = 0.f, p1 = 0.f;
#pragma unroll
        for (int j = 0; j < 8; ++j) {
            float v = (float)a[j] + (float)b[j] + efv[r] * wf[j];
            float hh = fmaxf(v, 0.f);
            p0 += hh * w2a[j];
            p1 += hh * w2b[j];
        }
#pragma unroll
        for (int m = 1; m < 16; m <<= 1) {
            p0 += __shfl_xor(p0, m, 64);
            p1 += __shfl_xor(p1, m, 64);
        }
        if (fl == 0) *(float2*)&out[(size_t)e * 2] = make_float2(p0 + b20, p1 + b21);
    }
}

// ---------------- launch ----------------

extern "C" void kernel_launch(void* const* d_in, const int* in_sizes, int n_in,
                              void* d_out, int out_size, void* d_ws, size_t ws_size,
                              hipStream_t stream) {
    const float* node_feats = (const float*)d_in[0];
    const float* edge_feats = (const float*)d_in[1];
    const int*   src = (const int*)d_in[2];
    const int*   dst = (const int*)d_in[3];
    const float* ws0 = (const float*)d_in[4];
    const float* wn0 = (const float*)d_in[5];
    const float* b0  = (const float*)d_in[6];
    const float* ws1 = (const float*)d_in[7];
    const float* wn1 = (const float*)d_in[8];
    const float* b1  = (const float*)d_in[9];
    const float* ws2 = (const float*)d_in[10];
    const float* wn2 = (const float*)d_in[11];
    const float* b2  = (const float*)d_in[12];
    const float* mw1 = (const float*)d_in[13];
    const float* mb1 = (const float*)d_in[14];
    const float* mw2 = (const float*)d_in[15];
    const float* mb2 = (const float*)d_in[16];
    float* out = (float*)d_out;

    char* ws = (char*)d_ws;
    size_t off = 0;
    auto alloc = [&](size_t bytes) {
        size_t o = off;
        off += (bytes + 511) & ~(size_t)511;
        return o;
    };
    ushort* nfb = (ushort*)(ws + alloc((size_t)N_NODES * F * 2));
    ushort* hb0 = (ushort*)(ws + alloc((size_t)N_NODES * F * 2));
    ushort* hb1 = (ushort*)(ws + alloc((size_t)N_NODES * F * 2));
    ushort* zsb = (ushort*)(ws + alloc((size_t)N_NODES * F * 2));
    int*   deg  = (int*)  (ws + alloc((size_t)N_NODES * 4));
    float* invd = (float*)(ws + alloc((size_t)N_NODES * 4));
    int*   rowp = (int*)  (ws + alloc(((size_t)N_NODES + 1) * 4));
    int*   incl = (int*)  (ws + alloc((size_t)N_NODES * 4));
    int*   bsum = (int*)  (ws + alloc((size_t)NB * 4));
    int*   boff = (int*)  (ws + alloc((size_t)NB * 4));
    int*   csrc = (int*)  (ws + alloc((size_t)N_EDGES * 4));
    int*   bcur = (int*)  (ws + alloc((size_t)NBUCK * 4));
    uint2* bstore = (uint2*)(ws + alloc((size_t)NBUCK * BCAP * 8));
    ushort* aw0 = (ushort*)(ws + alloc((size_t)128 * KW * 2));
    ushort* aw1 = (ushort*)(ws + alloc((size_t)128 * KW * 2));
    ushort* aw2 = (ushort*)(ws + alloc((size_t)128 * KW * 2));
    ushort* awS = (ushort*)(ws + alloc((size_t)128 * KS * 2));
    ushort* awD = (ushort*)(ws + alloc((size_t)128 * KD * 2));
    // aliases (lifetimes disjoint): zs in zsb; zd reuses nfb (dead after layer 0)
    _Float16* zs = (_Float16*)zsb;
    _Float16* zd = (_Float16*)nfb;

    // --- CSR build (bucketed) ---
    hipMemsetAsync(bcur, 0, (size_t)NBUCK * 4, stream);
    bucket_scatter<<<N_EDGES / 256, 256, 0, stream>>>(src, dst, bcur, bstore);
    bucket_deg<<<NBUCK, 256, 0, stream>>>(bstore, bcur, deg);
    scan1_kernel<<<NB, 1024, 0, stream>>>(deg, incl, bsum);
    scan2_kernel<<<1, 128, 0, stream>>>(bsum, boff, rowp);
    scan3_kernel<<<NB, 1024, 0, stream>>>(incl, deg, boff, rowp, invd);
    bucket_fill<<<NBUCK, 256, 0, stream>>>(bstore, bcur, rowp, csrc);

    // --- weight/feature prep ---
    prep_sage_w<<<(128 * KW + 255) / 256, 256, 0, stream>>>(ws0, wn0, b0, aw0);
    prep_sage_w<<<(128 * KW + 255) / 256, 256, 0, stream>>>(ws1, wn1, b1, aw1);
    prep_sage_w<<<(128 * KW + 255) / 256, 256, 0, stream>>>(ws2, wn2, b2, aw2);
    prep_zs_w<<<(128 * KS + 255) / 256, 256, 0, stream>>>(mw1, mb1, awS);
    prep_zd_w<<<(128 * KD + 255) / 256, 256, 0, stream>>>(mw1, awD);
    convert_bf16_kernel<<<(N_NODES * F / 8 + 255) / 256, 256, 0, stream>>>(node_feats, nfb);

    // --- 3 fused SAGE layers ---
    const ushort* hin = nfb;
    ushort* houts[3] = {hb0, hb1, hb0};
    const ushort* aws_[3] = {aw0, aw1, aw2};
    for (int l = 0; l < 3; ++l) {
        agg_sage_fused<<<N_NODES / 32, 256, 0, stream>>>(hin, csrc, rowp, invd, aws_[l], houts[l]);
        hin = houts[l];
    }

    // --- edge MLP ---
    mlp_z_mfma<<<(N_NODES / 32 + STILE - 1) / STILE, 256, 0, stream>>>(hb0, awS, awD, zs, zd);
    edge_final<<<N_EDGES / (16 * EROUNDS), 256, 0, stream>>>(
        zs, zd, edge_feats, src, dst, mw1, mw2, mb2, out);
}

// Round 7
// 833.318 us; speedup vs baseline: 1.6378x; 1.6378x over previous
//
#include <hip/hip_runtime.h>
#include <hip/hip_bf16.h>

#define N_NODES 100000
#define N_EDGES 1600000
#define F 128
#define KW 272          // sage padded K: 17 frags x 16
#define KS 144          // zs padded K: 128 + bias -> 9 frags
#define KD 128          // zd K: 8 frags
#define EROUNDS 8       // edge kernel: 16 edges/slot-round, 128 edges/block
#define NBUCK 512       // CSR buckets (dst>>8), 256 nodes each
#define BCAP 5120       // bucket capacity: full-bucket mean 4096, sd 64 -> +16 sigma
#define NB 98           // scan blocks: ceil(100000/1024)
#define CHUNK 8192      // edges per scatter block
#define NSBLK ((N_EDGES + CHUNK - 1) / CHUNK)   // 196

typedef short bf16x8 __attribute__((ext_vector_type(8)));
typedef float f32x16 __attribute__((ext_vector_type(16)));
typedef _Float16 half8 __attribute__((ext_vector_type(8)));
typedef _Float16 half4 __attribute__((ext_vector_type(4)));

__device__ __forceinline__ short f2bf(float x) {
    unsigned u = __builtin_bit_cast(unsigned, x);
    u += 0x7FFF + ((u >> 16) & 1);          // RNE
    return (short)(u >> 16);
}
__device__ __forceinline__ float bflo(unsigned u) {
    return __builtin_bit_cast(float, u << 16);
}
__device__ __forceinline__ float bfhi(unsigned u) {
    return __builtin_bit_cast(float, u & 0xFFFF0000u);
}

// ---------------- bucketed CSR build ----------------
// Phase 1: block-batched scatter. LDS histogram -> ONE global atomic per
// bucket per block (196 deep max chain, vs 3125 with per-edge atomics).
// Record packed to 4B: (dst&255)<<17 | src  (src < 2^17).
__global__ __launch_bounds__(256) void bucket_scatter(
    const int* __restrict__ src, const int* __restrict__ dst,
    int* __restrict__ bcur, unsigned* __restrict__ bstore) {
    __shared__ int hist[NBUCK];
    __shared__ unsigned pk[CHUNK];
    int t = threadIdx.x;
    int e0 = blockIdx.x * CHUNK;
    int n = N_EDGES - e0; if (n > CHUNK) n = CHUNK;
    for (int i = t; i < NBUCK; i += 256) hist[i] = 0;
    __syncthreads();
    // phase A: histogram + stage packed records in LDS
    for (int i = t; i < n; i += 256) {
        int d = dst[e0 + i];
        int s = src[e0 + i];
        pk[i] = ((unsigned)(d & 255) << 17) | (unsigned)s;
        atomicAdd(&hist[d >> 8], 1);
    }
    __syncthreads();
    // phase B: batch-reserve bucket space; hist becomes the running cursor
    for (int i = t; i < NBUCK; i += 256) {
        int c = hist[i];
        hist[i] = (c > 0) ? atomicAdd(&bcur[i], c) : 0;
    }
    __syncthreads();
    // phase C: scatter from LDS using LDS cursors
    for (int i = t; i < n; i += 256) {
        unsigned v = pk[i];
        int bk = (int)(v >> 17) | ((e0 + i) & 0);   // bucket needs full dst; recompute below
        // recompute bucket from dst high bits: stored only dst&255, so reload dst
        int d = dst[e0 + i];
        bk = d >> 8;
        int p = atomicAdd(&hist[bk], 1);
        if (p < BCAP) bstore[(size_t)bk * BCAP + p] = v;
    }
}

// Phase 2: per-bucket degree count via LDS atomics, coalesced deg write.
__global__ __launch_bounds__(256) void bucket_deg(const unsigned* __restrict__ bstore,
                                                  const int* __restrict__ bcur,
                                                  int* __restrict__ deg) {
    __shared__ int cnt[256];
    int b = blockIdx.x, t = threadIdx.x;
    cnt[t] = 0;
    __syncthreads();
    int n = bcur[b]; if (n > BCAP) n = BCAP;
    const unsigned* p = bstore + (size_t)b * BCAP;
    for (int i = t; i < n; i += 256) atomicAdd(&cnt[p[i] >> 17], 1);
    __syncthreads();
    int node = b * 256 + t;
    if (node < N_NODES) deg[node] = cnt[t];
}

// Multi-block scan: K1 per-block inclusive scans + block sums
__global__ __launch_bounds__(1024) void scan1_kernel(const int* __restrict__ deg,
                                                     int* __restrict__ incl,
                                                     int* __restrict__ bsum) {
    __shared__ int wsum[16];
    int t = threadIdx.x, lane = t & 63, wid = t >> 6;
    int i = blockIdx.x * 1024 + t;
    int v = (i < N_NODES) ? deg[i] : 0;
    int sc = v;
#pragma unroll
    for (int off = 1; off < 64; off <<= 1) {
        int u = __shfl_up(sc, off, 64);
        if (lane >= off) sc += u;
    }
    if (lane == 63) wsum[wid] = sc;
    __syncthreads();
    if (wid == 0) {
        int wv = (lane < 16) ? wsum[lane] : 0;
        int wi = wv;
#pragma unroll
        for (int off = 1; off < 16; off <<= 1) {
            int u = __shfl_up(wi, off, 64);
            if (lane >= off) wi += u;
        }
        if (lane < 16) wsum[lane] = wi - wv;
    }
    __syncthreads();
    int full = sc + wsum[wid];
    if (i < N_NODES) incl[i] = full;
    if (t == 1023) bsum[blockIdx.x] = full;
}

// K2: scan the 98 block sums (exclusive), write grand total to row_ptr[N]
__global__ void scan2_kernel(const int* __restrict__ bsum, int* __restrict__ boff,
                             int* __restrict__ row_ptr) {
    __shared__ int w0;
    int t = threadIdx.x, lane = t & 63, wid = t >> 6;
    int v = (t < NB) ? bsum[t] : 0;
    int sc = v;
#pragma unroll
    for (int off = 1; off < 64; off <<= 1) {
        int u = __shfl_up(sc, off, 64);
        if (lane >= off) sc += u;
    }
    if (wid == 0 && lane == 63) w0 = sc;
    __syncthreads();
    if (wid == 1) sc += w0;
    if (t < NB) boff[t] = sc - v;
    if (t == NB - 1) row_ptr[N_NODES] = sc;
}

// K3: exclusive row_ptr + inv_deg
__global__ __launch_bounds__(1024) void scan3_kernel(const int* __restrict__ incl,
                                                     const int* __restrict__ deg,
                                                     const int* __restrict__ boff,
                                                     int* __restrict__ row_ptr,
                                                     float* __restrict__ invd) {
    int i = blockIdx.x * 1024 + threadIdx.x;
    if (i >= N_NODES) return;
    int d = deg[i];
    row_ptr[i] = incl[i] - d + boff[blockIdx.x];
    invd[i] = 1.0f / (float)(d > 1 ? d : 1);
}

// Phase 3: per-bucket CSR fill; LDS cursors, writes land in a ~16KB L2 window.
__global__ __launch_bounds__(256) void bucket_fill(const unsigned* __restrict__ bstore,
                                                   const int* __restrict__ bcur,
                                                   const int* __restrict__ row_ptr,
                                                   int* __restrict__ csr_src) {
    __shared__ int cur[256];
    int b = blockIdx.x, t = threadIdx.x;
    int node = b * 256 + t;
    cur[t] = (node < N_NODES) ? row_ptr[node] : 0;
    __syncthreads();
    int n = bcur[b]; if (n > BCAP) n = BCAP;
    const unsigned* p = bstore + (size_t)b * BCAP;
    for (int i = t; i < n; i += 256) {
        unsigned e = p[i];
        int slot = atomicAdd(&cur[e >> 17], 1);
        csr_src[slot] = (int)(e & 0x1FFFF);
    }
}

// ---------------- fp32 -> bf16 convert ----------------

__global__ void convert_bf16_kernel(const float* __restrict__ in, ushort* __restrict__ out) {
    int idx = (blockIdx.x * 256 + threadIdx.x) * 8;
    float4 a = *(const float4*)&in[idx];
    float4 b = *(const float4*)&in[idx + 4];
    ushort o[8];
    o[0] = (ushort)f2bf(a.x); o[1] = (ushort)f2bf(a.y);
    o[2] = (ushort)f2bf(a.z); o[3] = (ushort)f2bf(a.w);
    o[4] = (ushort)f2bf(b.x); o[5] = (ushort)f2bf(b.y);
    o[6] = (ushort)f2bf(b.z); o[7] = (ushort)f2bf(b.w);
    *(uint4*)&out[idx] = *(uint4*)o;
}

// ---------------- weight prep ----------------

__global__ void prep_sage_w(const float* __restrict__ wsx, const float* __restrict__ wnx,
                            const float* __restrict__ b, ushort* __restrict__ aw) {
    int idx = blockIdx.x * 256 + threadIdx.x;
    if (idx >= 128 * KW) return;
    int h = idx / KW;
    int k = idx - h * KW;
    float v = 0.f;
    if (k < 128) v = wsx[(size_t)k * 128 + h];
    else if (k < 256) v = wnx[(size_t)(k - 128) * 128 + h];
    else if (k == 256) v = b[h];
    aw[idx] = (ushort)f2bf(v);
}

__global__ void prep_zs_w(const float* __restrict__ mw1, const float* __restrict__ mb1,
                          ushort* __restrict__ aw) {
    int idx = blockIdx.x * 256 + threadIdx.x;
    if (idx >= 128 * KS) return;
    int h = idx / KS;
    int k = idx - h * KS;
    float v = 0.f;
    if (k < 128) v = mw1[(size_t)k * 128 + h];
    else if (k == 128) v = mb1[h];
    aw[idx] = (ushort)f2bf(v);
}

__global__ void prep_zd_w(const float* __restrict__ mw1, ushort* __restrict__ aw) {
    int idx = blockIdx.x * 256 + threadIdx.x;
    if (idx >= 128 * KD) return;
    int h = idx / KD;
    int k = idx - h * KD;
    aw[idx] = (ushort)f2bf(mw1[(size_t)(128 + k) * 128 + h]);
}

// ---------------- fused agg + SAGE layer (32 nodes/block) ----------------
__global__ __launch_bounds__(256) void agg_sage_fused(
    const ushort* __restrict__ hb, const int* __restrict__ csr_src,
    const int* __restrict__ row_ptr, const float* __restrict__ inv_deg,
    const ushort* __restrict__ aw, ushort* __restrict__ hout) {
    __shared__ ushort sM[32 * 136];   // stride 68 dwords: agg writes conflict-free
    int t = threadIdx.x;
    int lane = t & 63, w = t >> 6;
    int l31 = lane & 31, hf = lane >> 5;

    bf16x8 afrag[17];
    const ushort* ap = aw + (size_t)(w * 32 + l31) * KW + hf * 8;
#pragma unroll
    for (int f = 0; f < 17; ++f) afrag[f] = *(const bf16x8*)(ap + f * 16);

    int n0 = blockIdx.x * 32;
    // phase 1: mean aggregation into LDS
    for (int j = 0; j < 8; ++j) {
        int node = n0 + w * 8 + j;
        int s = row_ptr[node], e = row_ptr[node + 1];
        float a0 = 0.f, a1 = 0.f;
        int i = s;
        for (; i + 4 <= e; i += 4) {
            int m0 = csr_src[i], m1 = csr_src[i + 1], m2 = csr_src[i + 2], m3 = csr_src[i + 3];
            unsigned u0 = *(const unsigned*)(hb + (size_t)m0 * F + lane * 2);
            unsigned u1 = *(const unsigned*)(hb + (size_t)m1 * F + lane * 2);
            unsigned u2 = *(const unsigned*)(hb + (size_t)m2 * F + lane * 2);
            unsigned u3 = *(const unsigned*)(hb + (size_t)m3 * F + lane * 2);
            a0 += bflo(u0) + bflo(u1) + bflo(u2) + bflo(u3);
            a1 += bfhi(u0) + bfhi(u1) + bfhi(u2) + bfhi(u3);
        }
        for (; i < e; ++i) {
            int mid = csr_src[i];
            unsigned u = *(const unsigned*)(hb + (size_t)mid * F + lane * 2);
            a0 += bflo(u);
            a1 += bfhi(u);
        }
        float iv = inv_deg[node];
        ushort o[2] = {(ushort)f2bf(a0 * iv), (ushort)f2bf(a1 * iv)};
        *(unsigned*)&sM[(w * 8 + j) * 136 + lane * 2] = *(unsigned*)o;
    }
    __syncthreads();

    // phase 2: MFMA
    int n = n0 + l31;
    const ushort* bs = hb + (size_t)n * F + hf * 8;
    f32x16 acc1, acc2;
#pragma unroll
    for (int r = 0; r < 16; ++r) { acc1[r] = 0.f; acc2[r] = 0.f; }
#pragma unroll
    for (int f = 0; f < 8; ++f) {
        bf16x8 b = *(const bf16x8*)(bs + f * 16);
        acc1 = __builtin_amdgcn_mfma_f32_32x32x16_bf16(afrag[f], b, acc1, 0, 0, 0);
    }
#pragma unroll
    for (int f = 0; f < 8; ++f) {
        bf16x8 b = *(const bf16x8*)&sM[l31 * 136 + hf * 8 + f * 16];
        acc2 = __builtin_amdgcn_mfma_f32_32x32x16_bf16(afrag[8 + f], b, acc2, 0, 0, 0);
    }
    bf16x8 bx;
#pragma unroll
    for (int j = 0; j < 8; ++j) bx[j] = 0;
    if (hf == 0) bx[0] = (short)0x3F80;   // k=256: bias row * 1.0
    acc2 = __builtin_amdgcn_mfma_f32_32x32x16_bf16(afrag[16], bx, acc2, 0, 0, 0);

#pragma unroll
    for (int g = 0; g < 4; ++g) {
        ushort o4[4];
#pragma unroll
        for (int j = 0; j < 4; ++j) {
            float v = acc1[g * 4 + j] + acc2[g * 4 + j];
            v = v > 0.f ? v : 0.01f * v;
            o4[j] = (ushort)f2bf(v);
        }
        *(uint2*)(hout + (size_t)n * F + w * 32 + g * 8 + hf * 4) = *(uint2*)o4;
    }
}

// ---------------- zs/zd precompute via MFMA ----------------
#define STILE 8
__global__ __launch_bounds__(256) void mlp_z_mfma(
    const ushort* __restrict__ hb, const ushort* __restrict__ aws,
    const ushort* __restrict__ awd, _Float16* __restrict__ zs,
    _Float16* __restrict__ zd) {
    int t = threadIdx.x;
    int lane = t & 63, w = t >> 6;
    int l31 = lane & 31, hf = lane >> 5;

    bf16x8 afs[9], afd[8];
    const ushort* aps = aws + (size_t)(w * 32 + l31) * KS + hf * 8;
    const ushort* apd = awd + (size_t)(w * 32 + l31) * KD + hf * 8;
#pragma unroll
    for (int f = 0; f < 9; ++f) afs[f] = *(const bf16x8*)(aps + f * 16);
#pragma unroll
    for (int f = 0; f < 8; ++f) afd[f] = *(const bf16x8*)(apd + f * 16);

    int tile0 = blockIdx.x * STILE;
    for (int tt = 0; tt < STILE; ++tt) {
        int tile = tile0 + tt;
        if (tile >= N_NODES / 32) break;
        int n = tile * 32 + l31;
        const ushort* bp = hb + (size_t)n * F + hf * 8;

        f32x16 accS, accD;
#pragma unroll
        for (int r = 0; r < 16; ++r) { accS[r] = 0.f; accD[r] = 0.f; }
#pragma unroll
        for (int f = 0; f < 8; ++f) {
            bf16x8 b = *(const bf16x8*)(bp + f * 16);
            accS = __builtin_amdgcn_mfma_f32_32x32x16_bf16(afs[f], b, accS, 0, 0, 0);
            accD = __builtin_amdgcn_mfma_f32_32x32x16_bf16(afd[f], b, accD, 0, 0, 0);
        }
        bf16x8 bx;
#pragma unroll
        for (int j = 0; j < 8; ++j) bx[j] = 0;
        if (hf == 0) bx[0] = (short)0x3F80;   // k=128: bias row * 1.0
        accS = __builtin_amdgcn_mfma_f32_32x32x16_bf16(afs[8], bx, accS, 0, 0, 0);

#pragma unroll
        for (int g = 0; g < 4; ++g) {
            half4 os, od;
#pragma unroll
            for (int j = 0; j < 4; ++j) {
                os[j] = (_Float16)accS[g * 4 + j];
                od[j] = (_Float16)accD[g * 4 + j];
            }
            int col = w * 32 + g * 8 + hf * 4;
            *(half4*)(zs + (size_t)n * F + col) = os;
            *(half4*)(zd + (size_t)n * F + col) = od;
        }
    }
}

// ---------------- final edge kernel ----------------
__global__ __launch_bounds__(256) void edge_final(
    const _Float16* __restrict__ zs, const _Float16* __restrict__ zd,
    const float* __restrict__ ef,
    const int* __restrict__ src, const int* __restrict__ dst,
    const float* __restrict__ mw1, const float* __restrict__ mw2,
    const float* __restrict__ mb2, float* __restrict__ out) {
    int t = threadIdx.x;
    int g = t >> 4;       // edge slot 0..15
    int fl = t & 15;      // feature chunk

    float wf[8], w2a[8], w2b[8];
#pragma unroll
    for (int j = 0; j < 8; ++j) {
        int feat = fl * 8 + j;
        wf[j]  = mw1[(size_t)256 * 128 + feat];
        float2 v = *(const float2*)&mw2[feat * 2];
        w2a[j] = v.x; w2b[j] = v.y;
    }
    float b20 = mb2[0], b21 = mb2[1];

    int e0 = blockIdx.x * (16 * EROUNDS);
    int isv[EROUNDS], idv[EROUNDS];
    float efv[EROUNDS];
#pragma unroll
    for (int r = 0; r < EROUNDS; ++r) {
        int e = e0 + r * 16 + g;
        isv[r] = src[e];
        idv[r] = dst[e];
        efv[r] = ef[e];
    }
#pragma unroll
    for (int r = 0; r < EROUNDS; ++r) {
        int e = e0 + r * 16 + g;
        half8 a = *(const half8*)(zs + (size_t)isv[r] * F + fl * 8);
        half8 b = *(const half8*)(zd + (size_t)idv[r] * F + fl * 8);
        float p0 = 0.f, p1 = 0.f;
#pragma unroll
        for (int j = 0; j < 8; ++j) {
            float v = (float)a[j] + (float)b[j] + efv[r] * wf[j];
            float hh = fmaxf(v, 0.f);
            p0 += hh * w2a[j];
            p1 += hh * w2b[j];
        }
#pragma unroll
        for (int m = 1; m < 16; m <<= 1) {
            p0 += __shfl_xor(p0, m, 64);
            p1 += __shfl_xor(p1, m, 64);
        }
        if (fl == 0) *(float2*)&out[(size_t)e * 2] = make_float2(p0 + b20, p1 + b21);
    }
}

// ---------------- launch ----------------

extern "C" void kernel_launch(void* const* d_in, const int* in_sizes, int n_in,
                              void* d_out, int out_size, void* d_ws, size_t ws_size,
                              hipStream_t stream) {
    const float* node_feats = (const float*)d_in[0];
    const float* edge_feats = (const float*)d_in[1];
    const int*   src = (const int*)d_in[2];
    const int*   dst = (const int*)d_in[3];
    const float* ws0 = (const float*)d_in[4];
    const float* wn0 = (const float*)d_in[5];
    const float* b0  = (const float*)d_in[6];
    const float* ws1 = (const float*)d_in[7];
    const float* wn1 = (const float*)d_in[8];
    const float* b1  = (const float*)d_in[9];
    const float* ws2 = (const float*)d_in[10];
    const float* wn2 = (const float*)d_in[11];
    const float* b2  = (const float*)d_in[12];
    const float* mw1 = (const float*)d_in[13];
    const float* mb1 = (const float*)d_in[14];
    const float* mw2 = (const float*)d_in[15];
    const float* mb2 = (const float*)d_in[16];
    float* out = (float*)d_out;

    char* ws = (char*)d_ws;
    size_t off = 0;
    auto alloc = [&](size_t bytes) {
        size_t o = off;
        off += (bytes + 511) & ~(size_t)511;
        return o;
    };
    ushort* nfb = (ushort*)(ws + alloc((size_t)N_NODES * F * 2));
    ushort* hb0 = (ushort*)(ws + alloc((size_t)N_NODES * F * 2));
    ushort* hb1 = (ushort*)(ws + alloc((size_t)N_NODES * F * 2));
    ushort* zsb = (ushort*)(ws + alloc((size_t)N_NODES * F * 2));
    int*   deg  = (int*)  (ws + alloc((size_t)N_NODES * 4));
    float* invd = (float*)(ws + alloc((size_t)N_NODES * 4));
    int*   rowp = (int*)  (ws + alloc(((size_t)N_NODES + 1) * 4));
    int*   incl = (int*)  (ws + alloc((size_t)N_NODES * 4));
    int*   bsum = (int*)  (ws + alloc((size_t)NB * 4));
    int*   boff = (int*)  (ws + alloc((size_t)NB * 4));
    int*   csrc = (int*)  (ws + alloc((size_t)N_EDGES * 4));
    int*   bcur = (int*)  (ws + alloc((size_t)NBUCK * 4));
    unsigned* bstore = (unsigned*)(ws + alloc((size_t)NBUCK * BCAP * 4));
    ushort* aw0 = (ushort*)(ws + alloc((size_t)128 * KW * 2));
    ushort* aw1 = (ushort*)(ws + alloc((size_t)128 * KW * 2));
    ushort* aw2 = (ushort*)(ws + alloc((size_t)128 * KW * 2));
    ushort* awS = (ushort*)(ws + alloc((size_t)128 * KS * 2));
    ushort* awD = (ushort*)(ws + alloc((size_t)128 * KD * 2));
    // aliases (lifetimes disjoint): zs in zsb; zd reuses nfb (dead after layer 0)
    _Float16* zs = (_Float16*)zsb;
    _Float16* zd = (_Float16*)nfb;

    // --- CSR build (bucketed, batched reservation) ---
    hipMemsetAsync(bcur, 0, (size_t)NBUCK * 4, stream);
    bucket_scatter<<<NSBLK, 256, 0, stream>>>(src, dst, bcur, bstore);
    bucket_deg<<<NBUCK, 256, 0, stream>>>(bstore, bcur, deg);
    scan1_kernel<<<NB, 1024, 0, stream>>>(deg, incl, bsum);
    scan2_kernel<<<1, 128, 0, stream>>>(bsum, boff, rowp);
    scan3_kernel<<<NB, 1024, 0, stream>>>(incl, deg, boff, rowp, invd);
    bucket_fill<<<NBUCK, 256, 0, stream>>>(bstore, bcur, rowp, csrc);

    // --- weight/feature prep ---
    prep_sage_w<<<(128 * KW + 255) / 256, 256, 0, stream>>>(ws0, wn0, b0, aw0);
    prep_sage_w<<<(128 * KW + 255) / 256, 256, 0, stream>>>(ws1, wn1, b1, aw1);
    prep_sage_w<<<(128 * KW + 255) / 256, 256, 0, stream>>>(ws2, wn2, b2, aw2);
    prep_zs_w<<<(128 * KS + 255) / 256, 256, 0, stream>>>(mw1, mb1, awS);
    prep_zd_w<<<(128 * KD + 255) / 256, 256, 0, stream>>>(mw1, awD);
    convert_bf16_kernel<<<(N_NODES * F / 8 + 255) / 256, 256, 0, stream>>>(node_feats, nfb);

    // --- 3 fused SAGE layers ---
    const ushort* hin = nfb;
    ushort* houts[3] = {hb0, hb1, hb0};
    const ushort* aws_[3] = {aw0, aw1, aw2};
    for (int l = 0; l < 3; ++l) {
        agg_sage_fused<<<N_NODES / 32, 256, 0, stream>>>(hin, csrc, rowp, invd, aws_[l], houts[l]);
        hin = houts[l];
    }

    // --- edge MLP ---
    mlp_z_mfma<<<(N_NODES / 32 + STILE - 1) / STILE, 256, 0, stream>>>(hb0, awS, awD, zs, zd);
    edge_final<<<N_EDGES / (16 * EROUNDS), 256, 0, stream>>>(
        zs, zd, edge_feats, src, dst, mw1, mw2, mb2, out);
}

// Round 8
// 584.786 us; speedup vs baseline: 2.3339x; 1.4250x over previous
//
#include <hip/hip_runtime.h>
#include <hip/hip_bf16.h>

#define N_NODES 100000
#define N_EDGES 1600000
#define F 128
#define KW 272          // sage padded K: 17 frags x 16
#define KS 144          // zs padded K: 128 + bias -> 9 frags
#define KD 128          // zd K: 8 frags
#define EROUNDS 8       // edge kernel: 16 edges/slot-round, 128 edges/block
#define NBUCK 512       // CSR buckets (dst>>8), 256 nodes each
#define BCAP 5120       // bucket capacity: full-bucket mean 4096, sd 64 -> +16 sigma
#define NB 98           // scan blocks: ceil(100000/1024)
#define CHUNK 8192      // edges per scatter block
#define NSBLK ((N_EDGES + CHUNK - 1) / CHUNK)   // 196

typedef short bf16x8 __attribute__((ext_vector_type(8)));
typedef float f32x16 __attribute__((ext_vector_type(16)));
typedef _Float16 half8 __attribute__((ext_vector_type(8)));
typedef _Float16 half4 __attribute__((ext_vector_type(4)));

__device__ __forceinline__ short f2bf(float x) {
    unsigned u = __builtin_bit_cast(unsigned, x);
    u += 0x7FFF + ((u >> 16) & 1);          // RNE
    return (short)(u >> 16);
}
__device__ __forceinline__ float bflo(unsigned u) {
    return __builtin_bit_cast(float, u << 16);
}
__device__ __forceinline__ float bfhi(unsigned u) {
    return __builtin_bit_cast(float, u & 0xFFFF0000u);
}
__device__ __forceinline__ void acc8(float* a, uint4 u) {
    a[0] += bflo(u.x); a[1] += bfhi(u.x);
    a[2] += bflo(u.y); a[3] += bfhi(u.y);
    a[4] += bflo(u.z); a[5] += bfhi(u.z);
    a[6] += bflo(u.w); a[7] += bfhi(u.w);
}

// ---------------- bucketed CSR build ----------------
// Phase 1: block-batched scatter. LDS histogram -> ONE global atomic per
// bucket per block (<=196 deep chains). Record packed 4B: (dst&255)<<17 | src.
__global__ __launch_bounds__(256) void bucket_scatter(
    const int* __restrict__ src, const int* __restrict__ dst,
    int* __restrict__ bcur, unsigned* __restrict__ bstore) {
    __shared__ int hist[NBUCK];
    __shared__ unsigned pk[CHUNK];
    int t = threadIdx.x;
    int e0 = blockIdx.x * CHUNK;
    int n = N_EDGES - e0; if (n > CHUNK) n = CHUNK;
    for (int i = t; i < NBUCK; i += 256) hist[i] = 0;
    __syncthreads();
    for (int i = t; i < n; i += 256) {
        int d = dst[e0 + i];
        int s = src[e0 + i];
        pk[i] = ((unsigned)(d & 255) << 17) | (unsigned)s;
        atomicAdd(&hist[d >> 8], 1);
    }
    __syncthreads();
    for (int i = t; i < NBUCK; i += 256) {
        int c = hist[i];
        hist[i] = (c > 0) ? atomicAdd(&bcur[i], c) : 0;
    }
    __syncthreads();
    for (int i = t; i < n; i += 256) {
        int bk = dst[e0 + i] >> 8;        // coalesced re-read (L2-hot)
        int p = atomicAdd(&hist[bk], 1);
        if (p < BCAP) bstore[(size_t)bk * BCAP + p] = pk[i];
    }
}

__global__ __launch_bounds__(256) void bucket_deg(const unsigned* __restrict__ bstore,
                                                  const int* __restrict__ bcur,
                                                  int* __restrict__ deg) {
    __shared__ int cnt[256];
    int b = blockIdx.x, t = threadIdx.x;
    cnt[t] = 0;
    __syncthreads();
    int n = bcur[b]; if (n > BCAP) n = BCAP;
    const unsigned* p = bstore + (size_t)b * BCAP;
    for (int i = t; i < n; i += 256) atomicAdd(&cnt[p[i] >> 17], 1);
    __syncthreads();
    int node = b * 256 + t;
    if (node < N_NODES) deg[node] = cnt[t];
}

__global__ __launch_bounds__(1024) void scan1_kernel(const int* __restrict__ deg,
                                                     int* __restrict__ incl,
                                                     int* __restrict__ bsum) {
    __shared__ int wsum[16];
    int t = threadIdx.x, lane = t & 63, wid = t >> 6;
    int i = blockIdx.x * 1024 + t;
    int v = (i < N_NODES) ? deg[i] : 0;
    int sc = v;
#pragma unroll
    for (int off = 1; off < 64; off <<= 1) {
        int u = __shfl_up(sc, off, 64);
        if (lane >= off) sc += u;
    }
    if (lane == 63) wsum[wid] = sc;
    __syncthreads();
    if (wid == 0) {
        int wv = (lane < 16) ? wsum[lane] : 0;
        int wi = wv;
#pragma unroll
        for (int off = 1; off < 16; off <<= 1) {
            int u = __shfl_up(wi, off, 64);
            if (lane >= off) wi += u;
        }
        if (lane < 16) wsum[lane] = wi - wv;
    }
    __syncthreads();
    int full = sc + wsum[wid];
    if (i < N_NODES) incl[i] = full;
    if (t == 1023) bsum[blockIdx.x] = full;
}

__global__ void scan2_kernel(const int* __restrict__ bsum, int* __restrict__ boff,
                             int* __restrict__ row_ptr) {
    __shared__ int w0;
    int t = threadIdx.x, lane = t & 63, wid = t >> 6;
    int v = (t < NB) ? bsum[t] : 0;
    int sc = v;
#pragma unroll
    for (int off = 1; off < 64; off <<= 1) {
        int u = __shfl_up(sc, off, 64);
        if (lane >= off) sc += u;
    }
    if (wid == 0 && lane == 63) w0 = sc;
    __syncthreads();
    if (wid == 1) sc += w0;
    if (t < NB) boff[t] = sc - v;
    if (t == NB - 1) row_ptr[N_NODES] = sc;
}

__global__ __launch_bounds__(1024) void scan3_kernel(const int* __restrict__ incl,
                                                     const int* __restrict__ deg,
                                                     const int* __restrict__ boff,
                                                     int* __restrict__ row_ptr,
                                                     float* __restrict__ invd) {
    int i = blockIdx.x * 1024 + threadIdx.x;
    if (i >= N_NODES) return;
    int d = deg[i];
    row_ptr[i] = incl[i] - d + boff[blockIdx.x];
    invd[i] = 1.0f / (float)(d > 1 ? d : 1);
}

__global__ __launch_bounds__(256) void bucket_fill(const unsigned* __restrict__ bstore,
                                                   const int* __restrict__ bcur,
                                                   const int* __restrict__ row_ptr,
                                                   int* __restrict__ csr_src) {
    __shared__ int cur[256];
    int b = blockIdx.x, t = threadIdx.x;
    int node = b * 256 + t;
    cur[t] = (node < N_NODES) ? row_ptr[node] : 0;
    __syncthreads();
    int n = bcur[b]; if (n > BCAP) n = BCAP;
    const unsigned* p = bstore + (size_t)b * BCAP;
    for (int i = t; i < n; i += 256) {
        unsigned e = p[i];
        int slot = atomicAdd(&cur[e >> 17], 1);
        csr_src[slot] = (int)(e & 0x1FFFF);
    }
}

// ---------------- fp32 -> bf16 convert ----------------

__global__ void convert_bf16_kernel(const float* __restrict__ in, ushort* __restrict__ out) {
    int idx = (blockIdx.x * 256 + threadIdx.x) * 8;
    float4 a = *(const float4*)&in[idx];
    float4 b = *(const float4*)&in[idx + 4];
    ushort o[8];
    o[0] = (ushort)f2bf(a.x); o[1] = (ushort)f2bf(a.y);
    o[2] = (ushort)f2bf(a.z); o[3] = (ushort)f2bf(a.w);
    o[4] = (ushort)f2bf(b.x); o[5] = (ushort)f2bf(b.y);
    o[6] = (ushort)f2bf(b.z); o[7] = (ushort)f2bf(b.w);
    *(uint4*)&out[idx] = *(uint4*)o;
}

// ---------------- weight prep ----------------

__global__ void prep_sage_w(const float* __restrict__ wsx, const float* __restrict__ wnx,
                            const float* __restrict__ b, ushort* __restrict__ aw) {
    int idx = blockIdx.x * 256 + threadIdx.x;
    if (idx >= 128 * KW) return;
    int h = idx / KW;
    int k = idx - h * KW;
    float v = 0.f;
    if (k < 128) v = wsx[(size_t)k * 128 + h];
    else if (k < 256) v = wnx[(size_t)(k - 128) * 128 + h];
    else if (k == 256) v = b[h];
    aw[idx] = (ushort)f2bf(v);
}

__global__ void prep_zs_w(const float* __restrict__ mw1, const float* __restrict__ mb1,
                          ushort* __restrict__ aw) {
    int idx = blockIdx.x * 256 + threadIdx.x;
    if (idx >= 128 * KS) return;
    int h = idx / KS;
    int k = idx - h * KS;
    float v = 0.f;
    if (k < 128) v = mw1[(size_t)k * 128 + h];
    else if (k == 128) v = mb1[h];
    aw[idx] = (ushort)f2bf(v);
}

__global__ void prep_zd_w(const float* __restrict__ mw1, ushort* __restrict__ aw) {
    int idx = blockIdx.x * 256 + threadIdx.x;
    if (idx >= 128 * KD) return;
    int h = idx / KD;
    int k = idx - h * KD;
    aw[idx] = (ushort)f2bf(mw1[(size_t)(128 + k) * 128 + h]);
}

// ---------------- fused agg + SAGE layer (32 nodes/block) ----------------
// Phase 1 (edge_final-style): 16 slots x 16 lanes; lane owns 8 feats (dwordx4
// row gathers); each slot does 2 nodes, K-loop unrolled x4 -> 16 gathers in
// flight per wave. Phase 2: weight-stationary MFMA (weights loaded AFTER the
// gather phase to keep its register budget low).
__global__ __launch_bounds__(256) void agg_sage_fused(
    const ushort* __restrict__ hb, const int* __restrict__ csr_src,
    const int* __restrict__ row_ptr, const float* __restrict__ inv_deg,
    const ushort* __restrict__ aw, ushort* __restrict__ hout) {
    __shared__ ushort sM[32 * 136];   // node stride 136 ushorts (272 B)
    int t = threadIdx.x;
    int lane = t & 63, w = t >> 6;
    int l31 = lane & 31, hf = lane >> 5;
    int slot = t >> 4;   // 0..15
    int fl = t & 15;     // feature chunk: 8 bf16 = 16 B

    int n0 = blockIdx.x * 32;
#pragma unroll
    for (int j = 0; j < 2; ++j) {
        int nb = j * 16 + slot;
        int node = n0 + nb;
        int s = row_ptr[node], e = row_ptr[node + 1];
        float acc[8] = {0.f, 0.f, 0.f, 0.f, 0.f, 0.f, 0.f, 0.f};
        int i = s;
        for (; i + 4 <= e; i += 4) {
            int m0 = csr_src[i], m1 = csr_src[i + 1], m2 = csr_src[i + 2], m3 = csr_src[i + 3];
            uint4 u0 = *(const uint4*)(hb + (size_t)m0 * F + fl * 8);
            uint4 u1 = *(const uint4*)(hb + (size_t)m1 * F + fl * 8);
            uint4 u2 = *(const uint4*)(hb + (size_t)m2 * F + fl * 8);
            uint4 u3 = *(const uint4*)(hb + (size_t)m3 * F + fl * 8);
            acc8(acc, u0); acc8(acc, u1); acc8(acc, u2); acc8(acc, u3);
        }
        for (; i < e; ++i) {
            int m = csr_src[i];
            uint4 u = *(const uint4*)(hb + (size_t)m * F + fl * 8);
            acc8(acc, u);
        }
        float iv = inv_deg[node];
        ushort o[8];
#pragma unroll
        for (int k = 0; k < 8; ++k) o[k] = (ushort)f2bf(acc[k] * iv);
        *(uint4*)&sM[nb * 136 + fl * 8] = *(uint4*)o;
    }

    // load weight fragments while the barrier drains
    bf16x8 afrag[17];
    const ushort* ap = aw + (size_t)(w * 32 + l31) * KW + hf * 8;
#pragma unroll
    for (int f = 0; f < 17; ++f) afrag[f] = *(const bf16x8*)(ap + f * 16);
    __syncthreads();

    // phase 2: MFMA
    int n = n0 + l31;
    const ushort* bs = hb + (size_t)n * F + hf * 8;
    f32x16 acc1, acc2;
#pragma unroll
    for (int r = 0; r < 16; ++r) { acc1[r] = 0.f; acc2[r] = 0.f; }
#pragma unroll
    for (int f = 0; f < 8; ++f) {
        bf16x8 b = *(const bf16x8*)(bs + f * 16);
        acc1 = __builtin_amdgcn_mfma_f32_32x32x16_bf16(afrag[f], b, acc1, 0, 0, 0);
    }
#pragma unroll
    for (int f = 0; f < 8; ++f) {
        bf16x8 b = *(const bf16x8*)&sM[l31 * 136 + hf * 8 + f * 16];
        acc2 = __builtin_amdgcn_mfma_f32_32x32x16_bf16(afrag[8 + f], b, acc2, 0, 0, 0);
    }
    bf16x8 bx;
#pragma unroll
    for (int j = 0; j < 8; ++j) bx[j] = 0;
    if (hf == 0) bx[0] = (short)0x3F80;   // k=256: bias row * 1.0
    acc2 = __builtin_amdgcn_mfma_f32_32x32x16_bf16(afrag[16], bx, acc2, 0, 0, 0);

#pragma unroll
    for (int g = 0; g < 4; ++g) {
        ushort o4[4];
#pragma unroll
        for (int j = 0; j < 4; ++j) {
            float v = acc1[g * 4 + j] + acc2[g * 4 + j];
            v = v > 0.f ? v : 0.01f * v;
            o4[j] = (ushort)f2bf(v);
        }
        *(uint2*)(hout + (size_t)n * F + w * 32 + g * 8 + hf * 4) = *(uint2*)o4;
    }
}

// ---------------- zs/zd precompute via MFMA ----------------
#define STILE 8
__global__ __launch_bounds__(256) void mlp_z_mfma(
    const ushort* __restrict__ hb, const ushort* __restrict__ aws,
    const ushort* __restrict__ awd, _Float16* __restrict__ zs,
    _Float16* __restrict__ zd) {
    int t = threadIdx.x;
    int lane = t & 63, w = t >> 6;
    int l31 = lane & 31, hf = lane >> 5;

    bf16x8 afs[9], afd[8];
    const ushort* aps = aws + (size_t)(w * 32 + l31) * KS + hf * 8;
    const ushort* apd = awd + (size_t)(w * 32 + l31) * KD + hf * 8;
#pragma unroll
    for (int f = 0; f < 9; ++f) afs[f] = *(const bf16x8*)(aps + f * 16);
#pragma unroll
    for (int f = 0; f < 8; ++f) afd[f] = *(const bf16x8*)(apd + f * 16);

    int tile0 = blockIdx.x * STILE;
    for (int tt = 0; tt < STILE; ++tt) {
        int tile = tile0 + tt;
        if (tile >= N_NODES / 32) break;
        int n = tile * 32 + l31;
        const ushort* bp = hb + (size_t)n * F + hf * 8;

        f32x16 accS, accD;
#pragma unroll
        for (int r = 0; r < 16; ++r) { accS[r] = 0.f; accD[r] = 0.f; }
#pragma unroll
        for (int f = 0; f < 8; ++f) {
            bf16x8 b = *(const bf16x8*)(bp + f * 16);
            accS = __builtin_amdgcn_mfma_f32_32x32x16_bf16(afs[f], b, accS, 0, 0, 0);
            accD = __builtin_amdgcn_mfma_f32_32x32x16_bf16(afd[f], b, accD, 0, 0, 0);
        }
        bf16x8 bx;
#pragma unroll
        for (int j = 0; j < 8; ++j) bx[j] = 0;
        if (hf == 0) bx[0] = (short)0x3F80;   // k=128: bias row * 1.0
        accS = __builtin_amdgcn_mfma_f32_32x32x16_bf16(afs[8], bx, accS, 0, 0, 0);

#pragma unroll
        for (int g = 0; g < 4; ++g) {
            half4 os, od;
#pragma unroll
            for (int j = 0; j < 4; ++j) {
                os[j] = (_Float16)accS[g * 4 + j];
                od[j] = (_Float16)accD[g * 4 + j];
            }
            int col = w * 32 + g * 8 + hf * 4;
            *(half4*)(zs + (size_t)n * F + col) = os;
            *(half4*)(zd + (size_t)n * F + col) = od;
        }
    }
}

// ---------------- final edge kernel ----------------
__global__ __launch_bounds__(256) void edge_final(
    const _Float16* __restrict__ zs, const _Float16* __restrict__ zd,
    const float* __restrict__ ef,
    const int* __restrict__ src, const int* __restrict__ dst,
    const float* __restrict__ mw1, const float* __restrict__ mw2,
    const float* __restrict__ mb2, float* __restrict__ out) {
    int t = threadIdx.x;
    int g = t >> 4;       // edge slot 0..15
    int fl = t & 15;      // feature chunk

    float wf[8], w2a[8], w2b[8];
#pragma unroll
    for (int j = 0; j < 8; ++j) {
        int feat = fl * 8 + j;
        wf[j]  = mw1[(size_t)256 * 128 + feat];
        float2 v = *(const float2*)&mw2[feat * 2];
        w2a[j] = v.x; w2b[j] = v.y;
    }
    float b20 = mb2[0], b21 = mb2[1];

    int e0 = blockIdx.x * (16 * EROUNDS);
    int isv[EROUNDS], idv[EROUNDS];
    float efv[EROUNDS];
#pragma unroll
    for (int r = 0; r < EROUNDS; ++r) {
        int e = e0 + r * 16 + g;
        isv[r] = src[e];
        idv[r] = dst[e];
        efv[r] = ef[e];
    }
#pragma unroll
    for (int r = 0; r < EROUNDS; ++r) {
        int e = e0 + r * 16 + g;
        half8 a = *(const half8*)(zs + (size_t)isv[r] * F + fl * 8);
        half8 b = *(const half8*)(zd + (size_t)idv[r] * F + fl * 8);
        float p0 = 0.f, p1 = 0.f;
#pragma unroll
        for (int j = 0; j < 8; ++j) {
            float v = (float)a[j] + (float)b[j] + efv[r] * wf[j];
            float hh = fmaxf(v, 0.f);
            p0 += hh * w2a[j];
            p1 += hh * w2b[j];
        }
#pragma unroll
        for (int m = 1; m < 16; m <<= 1) {
            p0 += __shfl_xor(p0, m, 64);
            p1 += __shfl_xor(p1, m, 64);
        }
        if (fl == 0) *(float2*)&out[(size_t)e * 2] = make_float2(p0 + b20, p1 + b21);
    }
}

// ---------------- launch ----------------

extern "C" void kernel_launch(void* const* d_in, const int* in_sizes, int n_in,
                              void* d_out, int out_size, void* d_ws, size_t ws_size,
                              hipStream_t stream) {
    const float* node_feats = (const float*)d_in[0];
    const float* edge_feats = (const float*)d_in[1];
    const int*   src = (const int*)d_in[2];
    const int*   dst = (const int*)d_in[3];
    const float* ws0 = (const float*)d_in[4];
    const float* wn0 = (const float*)d_in[5];
    const float* b0  = (const float*)d_in[6];
    const float* ws1 = (const float*)d_in[7];
    const float* wn1 = (const float*)d_in[8];
    const float* b1  = (const float*)d_in[9];
    const float* ws2 = (const float*)d_in[10];
    const float* wn2 = (const float*)d_in[11];
    const float* b2  = (const float*)d_in[12];
    const float* mw1 = (const float*)d_in[13];
    const float* mb1 = (const float*)d_in[14];
    const float* mw2 = (const float*)d_in[15];
    const float* mb2 = (const float*)d_in[16];
    float* out = (float*)d_out;

    char* ws = (char*)d_ws;
    size_t off = 0;
    auto alloc = [&](size_t bytes) {
        size_t o = off;
        off += (bytes + 511) & ~(size_t)511;
        return o;
    };
    ushort* nfb = (ushort*)(ws + alloc((size_t)N_NODES * F * 2));
    ushort* hb0 = (ushort*)(ws + alloc((size_t)N_NODES * F * 2));
    ushort* hb1 = (ushort*)(ws + alloc((size_t)N_NODES * F * 2));
    ushort* zsb = (ushort*)(ws + alloc((size_t)N_NODES * F * 2));
    int*   deg  = (int*)  (ws + alloc((size_t)N_NODES * 4));
    float* invd = (float*)(ws + alloc((size_t)N_NODES * 4));
    int*   rowp = (int*)  (ws + alloc(((size_t)N_NODES + 1) * 4));
    int*   incl = (int*)  (ws + alloc((size_t)N_NODES * 4));
    int*   bsum = (int*)  (ws + alloc((size_t)NB * 4));
    int*   boff = (int*)  (ws + alloc((size_t)NB * 4));
    int*   csrc = (int*)  (ws + alloc((size_t)N_EDGES * 4));
    int*   bcur = (int*)  (ws + alloc((size_t)NBUCK * 4));
    unsigned* bstore = (unsigned*)(ws + alloc((size_t)NBUCK * BCAP * 4));
    ushort* aw0 = (ushort*)(ws + alloc((size_t)128 * KW * 2));
    ushort* aw1 = (ushort*)(ws + alloc((size_t)128 * KW * 2));
    ushort* aw2 = (ushort*)(ws + alloc((size_t)128 * KW * 2));
    ushort* awS = (ushort*)(ws + alloc((size_t)128 * KS * 2));
    ushort* awD = (ushort*)(ws + alloc((size_t)128 * KD * 2));
    // aliases (lifetimes disjoint): zs in zsb; zd reuses nfb (dead after layer 0)
    _Float16* zs = (_Float16*)zsb;
    _Float16* zd = (_Float16*)nfb;

    // --- CSR build (bucketed, batched reservation) ---
    hipMemsetAsync(bcur, 0, (size_t)NBUCK * 4, stream);
    bucket_scatter<<<NSBLK, 256, 0, stream>>>(src, dst, bcur, bstore);
    bucket_deg<<<NBUCK, 256, 0, stream>>>(bstore, bcur, deg);
    scan1_kernel<<<NB, 1024, 0, stream>>>(deg, incl, bsum);
    scan2_kernel<<<1, 128, 0, stream>>>(bsum, boff, rowp);
    scan3_kernel<<<NB, 1024, 0, stream>>>(incl, deg, boff, rowp, invd);
    bucket_fill<<<NBUCK, 256, 0, stream>>>(bstore, bcur, rowp, csrc);

    // --- weight/feature prep ---
    prep_sage_w<<<(128 * KW + 255) / 256, 256, 0, stream>>>(ws0, wn0, b0, aw0);
    prep_sage_w<<<(128 * KW + 255) / 256, 256, 0, stream>>>(ws1, wn1, b1, aw1);
    prep_sage_w<<<(128 * KW + 255) / 256, 256, 0, stream>>>(ws2, wn2, b2, aw2);
    prep_zs_w<<<(128 * KS + 255) / 256, 256, 0, stream>>>(mw1, mb1, awS);
    prep_zd_w<<<(128 * KD + 255) / 256, 256, 0, stream>>>(mw1, awD);
    convert_bf16_kernel<<<(N_NODES * F / 8 + 255) / 256, 256, 0, stream>>>(node_feats, nfb);

    // --- 3 fused SAGE layers ---
    const ushort* hin = nfb;
    ushort* houts[3] = {hb0, hb1, hb0};
    const ushort* aws_[3] = {aw0, aw1, aw2};
    for (int l = 0; l < 3; ++l) {
        agg_sage_fused<<<N_NODES / 32, 256, 0, stream>>>(hin, csrc, rowp, invd, aws_[l], houts[l]);
        hin = houts[l];
    }

    // --- edge MLP ---
    mlp_z_mfma<<<(N_NODES / 32 + STILE - 1) / STILE, 256, 0, stream>>>(hb0, awS, awD, zs, zd);
    edge_final<<<N_EDGES / (16 * EROUNDS), 256, 0, stream>>>(
        zs, zd, edge_feats, src, dst, mw1, mw2, mb2, out);
}

// Round 9
// 546.802 us; speedup vs baseline: 2.4960x; 1.0695x over previous
//
#include <hip/hip_runtime.h>
#include <hip/hip_bf16.h>

#define N_NODES 100000
#define N_EDGES 1600000
#define F 128
#define KW 272          // sage padded K: 17 frags x 16
#define KS 144          // zs padded K: 128 + bias -> 9 frags
#define KD 128          // zd K: 8 frags
#define EROUNDS 8       // edge kernel: 16 edges/slot-round, 128 edges/block
#define NBUCK 512       // CSR buckets (dst>>8), 256 nodes each
#define BCAP 5120       // bucket capacity: full-bucket mean 4096, sd 64 -> +16 sigma
#define NB 98           // scan blocks: ceil(100000/1024)
#define CHUNK 8192      // edges per scatter block
#define NSBLK ((N_EDGES + CHUNK - 1) / CHUNK)   // 196

typedef short bf16x8 __attribute__((ext_vector_type(8)));
typedef float f32x16 __attribute__((ext_vector_type(16)));
typedef _Float16 half8 __attribute__((ext_vector_type(8)));
typedef _Float16 half4 __attribute__((ext_vector_type(4)));
typedef _Float16 half2v __attribute__((ext_vector_type(2)));

__device__ __forceinline__ short f2bf(float x) {
    unsigned u = __builtin_bit_cast(unsigned, x);
    u += 0x7FFF + ((u >> 16) & 1);          // RNE
    return (short)(u >> 16);
}
__device__ __forceinline__ float bflo(unsigned u) {
    return __builtin_bit_cast(float, u << 16);
}
__device__ __forceinline__ float bfhi(unsigned u) {
    return __builtin_bit_cast(float, u & 0xFFFF0000u);
}
__device__ __forceinline__ void acc8(float* a, uint4 u) {
    a[0] += bflo(u.x); a[1] += bfhi(u.x);
    a[2] += bflo(u.y); a[3] += bfhi(u.y);
    a[4] += bflo(u.z); a[5] += bfhi(u.z);
    a[6] += bflo(u.w); a[7] += bfhi(u.w);
}

// ---------------- bucketed CSR build ----------------
__global__ __launch_bounds__(256) void bucket_scatter(
    const int* __restrict__ src, const int* __restrict__ dst,
    int* __restrict__ bcur, unsigned* __restrict__ bstore) {
    __shared__ int hist[NBUCK];
    __shared__ unsigned pk[CHUNK];
    int t = threadIdx.x;
    int e0 = blockIdx.x * CHUNK;
    int n = N_EDGES - e0; if (n > CHUNK) n = CHUNK;
    for (int i = t; i < NBUCK; i += 256) hist[i] = 0;
    __syncthreads();
    for (int i = t; i < n; i += 256) {
        int d = dst[e0 + i];
        int s = src[e0 + i];
        pk[i] = ((unsigned)(d & 255) << 17) | (unsigned)s;
        atomicAdd(&hist[d >> 8], 1);
    }
    __syncthreads();
    for (int i = t; i < NBUCK; i += 256) {
        int c = hist[i];
        hist[i] = (c > 0) ? atomicAdd(&bcur[i], c) : 0;
    }
    __syncthreads();
    for (int i = t; i < n; i += 256) {
        int bk = dst[e0 + i] >> 8;        // coalesced re-read (L2-hot)
        int p = atomicAdd(&hist[bk], 1);
        if (p < BCAP) bstore[(size_t)bk * BCAP + p] = pk[i];
    }
}

__global__ __launch_bounds__(256) void bucket_deg(const unsigned* __restrict__ bstore,
                                                  const int* __restrict__ bcur,
                                                  int* __restrict__ deg) {
    __shared__ int cnt[256];
    int b = blockIdx.x, t = threadIdx.x;
    cnt[t] = 0;
    __syncthreads();
    int n = bcur[b]; if (n > BCAP) n = BCAP;
    const unsigned* p = bstore + (size_t)b * BCAP;
    for (int i = t; i < n; i += 256) atomicAdd(&cnt[p[i] >> 17], 1);
    __syncthreads();
    int node = b * 256 + t;
    if (node < N_NODES) deg[node] = cnt[t];
}

__global__ __launch_bounds__(1024) void scan1_kernel(const int* __restrict__ deg,
                                                     int* __restrict__ incl,
                                                     int* __restrict__ bsum) {
    __shared__ int wsum[16];
    int t = threadIdx.x, lane = t & 63, wid = t >> 6;
    int i = blockIdx.x * 1024 + t;
    int v = (i < N_NODES) ? deg[i] : 0;
    int sc = v;
#pragma unroll
    for (int off = 1; off < 64; off <<= 1) {
        int u = __shfl_up(sc, off, 64);
        if (lane >= off) sc += u;
    }
    if (lane == 63) wsum[wid] = sc;
    __syncthreads();
    if (wid == 0) {
        int wv = (lane < 16) ? wsum[lane] : 0;
        int wi = wv;
#pragma unroll
        for (int off = 1; off < 16; off <<= 1) {
            int u = __shfl_up(wi, off, 64);
            if (lane >= off) wi += u;
        }
        if (lane < 16) wsum[lane] = wi - wv;
    }
    __syncthreads();
    int full = sc + wsum[wid];
    if (i < N_NODES) incl[i] = full;
    if (t == 1023) bsum[blockIdx.x] = full;
}

__global__ void scan2_kernel(const int* __restrict__ bsum, int* __restrict__ boff,
                             int* __restrict__ row_ptr) {
    __shared__ int w0;
    int t = threadIdx.x, lane = t & 63, wid = t >> 6;
    int v = (t < NB) ? bsum[t] : 0;
    int sc = v;
#pragma unroll
    for (int off = 1; off < 64; off <<= 1) {
        int u = __shfl_up(sc, off, 64);
        if (lane >= off) sc += u;
    }
    if (wid == 0 && lane == 63) w0 = sc;
    __syncthreads();
    if (wid == 1) sc += w0;
    if (t < NB) boff[t] = sc - v;
    if (t == NB - 1) row_ptr[N_NODES] = sc;
}

__global__ __launch_bounds__(1024) void scan3_kernel(const int* __restrict__ incl,
                                                     const int* __restrict__ deg,
                                                     const int* __restrict__ boff,
                                                     int* __restrict__ row_ptr,
                                                     float* __restrict__ invd) {
    int i = blockIdx.x * 1024 + threadIdx.x;
    if (i >= N_NODES) return;
    int d = deg[i];
    row_ptr[i] = incl[i] - d + boff[blockIdx.x];
    invd[i] = 1.0f / (float)(d > 1 ? d : 1);
}

__global__ __launch_bounds__(256) void bucket_fill(const unsigned* __restrict__ bstore,
                                                   const int* __restrict__ bcur,
                                                   const int* __restrict__ row_ptr,
                                                   int* __restrict__ csr_src) {
    __shared__ int cur[256];
    int b = blockIdx.x, t = threadIdx.x;
    int node = b * 256 + t;
    cur[t] = (node < N_NODES) ? row_ptr[node] : 0;
    __syncthreads();
    int n = bcur[b]; if (n > BCAP) n = BCAP;
    const unsigned* p = bstore + (size_t)b * BCAP;
    for (int i = t; i < n; i += 256) {
        unsigned e = p[i];
        int slot = atomicAdd(&cur[e >> 17], 1);
        csr_src[slot] = (int)(e & 0x1FFFF);
    }
}

// ---------------- unified prep: 5 weight transposes + bf16 convert ----------
// block ranges: [0,136) aw0 | [136,272) aw1 | [272,408) aw2 |
//               [408,480) awS | [480,544) awD | [544,6794) convert
__global__ __launch_bounds__(256) void prep_all(
    const float* __restrict__ ws0, const float* __restrict__ wn0, const float* __restrict__ b0,
    const float* __restrict__ ws1, const float* __restrict__ wn1, const float* __restrict__ b1,
    const float* __restrict__ ws2, const float* __restrict__ wn2, const float* __restrict__ b2,
    const float* __restrict__ mw1, const float* __restrict__ mb1,
    ushort* __restrict__ aw0, ushort* __restrict__ aw1, ushort* __restrict__ aw2,
    ushort* __restrict__ awS, ushort* __restrict__ awD,
    const float* __restrict__ nf, ushort* __restrict__ nfb) {
    int b = blockIdx.x, t = threadIdx.x;
    if (b < 408) {
        const float* wsx; const float* wnx; const float* bb; ushort* aw;
        int rb;
        if (b < 136)      { wsx = ws0; wnx = wn0; bb = b0; aw = aw0; rb = b; }
        else if (b < 272) { wsx = ws1; wnx = wn1; bb = b1; aw = aw1; rb = b - 136; }
        else              { wsx = ws2; wnx = wn2; bb = b2; aw = aw2; rb = b - 272; }
        int idx = rb * 256 + t;
        int h = idx / KW;
        int k = idx - h * KW;
        float v = 0.f;
        if (k < 128) v = wsx[(size_t)k * 128 + h];
        else if (k < 256) v = wnx[(size_t)(k - 128) * 128 + h];
        else if (k == 256) v = bb[h];
        aw[idx] = (ushort)f2bf(v);
    } else if (b < 480) {
        int idx = (b - 408) * 256 + t;
        int h = idx / KS;
        int k = idx - h * KS;
        float v = 0.f;
        if (k < 128) v = mw1[(size_t)k * 128 + h];
        else if (k == 128) v = mb1[h];
        awS[idx] = (ushort)f2bf(v);
    } else if (b < 544) {
        int idx = (b - 480) * 256 + t;
        int h = idx >> 7;
        int k = idx & 127;
        awD[idx] = (ushort)f2bf(mw1[(size_t)(128 + k) * 128 + h]);
    } else {
        int idx = ((b - 544) * 256 + t) * 8;
        float4 a = *(const float4*)&nf[idx];
        float4 c = *(const float4*)&nf[idx + 4];
        ushort o[8];
        o[0] = (ushort)f2bf(a.x); o[1] = (ushort)f2bf(a.y);
        o[2] = (ushort)f2bf(a.z); o[3] = (ushort)f2bf(a.w);
        o[4] = (ushort)f2bf(c.x); o[5] = (ushort)f2bf(c.y);
        o[6] = (ushort)f2bf(c.z); o[7] = (ushort)f2bf(c.w);
        *(uint4*)&nfb[idx] = *(uint4*)o;
    }
}

// ---------------- fused agg + SAGE layer (32 nodes/block) ----------------
// Phase 1: 16 slots x 16 lanes, dwordx4 row gathers, unroll x8.
// Phase 2: weight-stationary MFMA. WITH_Z (layer 2): h3 stays in LDS only;
// zs/zd computed in-kernel via 17 more MFMAs (replaces mlp_z + h3 round-trip).
template <bool WITH_Z>
__global__ __launch_bounds__(256) void agg_sage_fused(
    const ushort* __restrict__ hb, const int* __restrict__ csr_src,
    const int* __restrict__ row_ptr, const float* __restrict__ inv_deg,
    const ushort* __restrict__ aw, ushort* __restrict__ hout,
    const ushort* __restrict__ aws, const ushort* __restrict__ awd,
    _Float16* __restrict__ zs, _Float16* __restrict__ zd) {
    __shared__ ushort sM[32 * 136];   // node stride 136 ushorts (272 B)
    int t = threadIdx.x;
    int lane = t & 63, w = t >> 6;
    int l31 = lane & 31, hf = lane >> 5;
    int slot = t >> 4;   // 0..15
    int fl = t & 15;     // feature chunk: 8 bf16 = 16 B

    int n0 = blockIdx.x * 32;
#pragma unroll
    for (int j = 0; j < 2; ++j) {
        int nb = j * 16 + slot;
        int node = n0 + nb;
        int s = row_ptr[node], e = row_ptr[node + 1];
        float acc[8] = {0.f, 0.f, 0.f, 0.f, 0.f, 0.f, 0.f, 0.f};
        int i = s;
        for (; i + 8 <= e; i += 8) {
            uint4 u0 = *(const uint4*)(hb + (size_t)csr_src[i] * F + fl * 8);
            uint4 u1 = *(const uint4*)(hb + (size_t)csr_src[i + 1] * F + fl * 8);
            uint4 u2 = *(const uint4*)(hb + (size_t)csr_src[i + 2] * F + fl * 8);
            uint4 u3 = *(const uint4*)(hb + (size_t)csr_src[i + 3] * F + fl * 8);
            uint4 u4 = *(const uint4*)(hb + (size_t)csr_src[i + 4] * F + fl * 8);
            uint4 u5 = *(const uint4*)(hb + (size_t)csr_src[i + 5] * F + fl * 8);
            uint4 u6 = *(const uint4*)(hb + (size_t)csr_src[i + 6] * F + fl * 8);
            uint4 u7 = *(const uint4*)(hb + (size_t)csr_src[i + 7] * F + fl * 8);
            acc8(acc, u0); acc8(acc, u1); acc8(acc, u2); acc8(acc, u3);
            acc8(acc, u4); acc8(acc, u5); acc8(acc, u6); acc8(acc, u7);
        }
        for (; i + 4 <= e; i += 4) {
            uint4 u0 = *(const uint4*)(hb + (size_t)csr_src[i] * F + fl * 8);
            uint4 u1 = *(const uint4*)(hb + (size_t)csr_src[i + 1] * F + fl * 8);
            uint4 u2 = *(const uint4*)(hb + (size_t)csr_src[i + 2] * F + fl * 8);
            uint4 u3 = *(const uint4*)(hb + (size_t)csr_src[i + 3] * F + fl * 8);
            acc8(acc, u0); acc8(acc, u1); acc8(acc, u2); acc8(acc, u3);
        }
        for (; i < e; ++i) {
            uint4 u = *(const uint4*)(hb + (size_t)csr_src[i] * F + fl * 8);
            acc8(acc, u);
        }
        float iv = inv_deg[node];
        ushort o[8];
#pragma unroll
        for (int k = 0; k < 8; ++k) o[k] = (ushort)f2bf(acc[k] * iv);
        *(uint4*)&sM[nb * 136 + fl * 8] = *(uint4*)o;
    }

    // load weight fragments while the barrier drains
    bf16x8 afrag[17];
    const ushort* ap = aw + (size_t)(w * 32 + l31) * KW + hf * 8;
#pragma unroll
    for (int f = 0; f < 17; ++f) afrag[f] = *(const bf16x8*)(ap + f * 16);
    __syncthreads();

    // phase 2: MFMA
    int n = n0 + l31;
    const ushort* bs = hb + (size_t)n * F + hf * 8;
    f32x16 acc1, acc2;
#pragma unroll
    for (int r = 0; r < 16; ++r) { acc1[r] = 0.f; acc2[r] = 0.f; }
#pragma unroll
    for (int f = 0; f < 8; ++f) {
        bf16x8 b = *(const bf16x8*)(bs + f * 16);
        acc1 = __builtin_amdgcn_mfma_f32_32x32x16_bf16(afrag[f], b, acc1, 0, 0, 0);
    }
#pragma unroll
    for (int f = 0; f < 8; ++f) {
        bf16x8 b = *(const bf16x8*)&sM[l31 * 136 + hf * 8 + f * 16];
        acc2 = __builtin_amdgcn_mfma_f32_32x32x16_bf16(afrag[8 + f], b, acc2, 0, 0, 0);
    }
    bf16x8 bx;
#pragma unroll
    for (int j = 0; j < 8; ++j) bx[j] = 0;
    if (hf == 0) bx[0] = (short)0x3F80;   // k=256: bias row * 1.0
    acc2 = __builtin_amdgcn_mfma_f32_32x32x16_bf16(afrag[16], bx, acc2, 0, 0, 0);

    if (!WITH_Z) {
#pragma unroll
        for (int g = 0; g < 4; ++g) {
            ushort o4[4];
#pragma unroll
            for (int j = 0; j < 4; ++j) {
                float v = acc1[g * 4 + j] + acc2[g * 4 + j];
                v = v > 0.f ? v : 0.01f * v;
                o4[j] = (ushort)f2bf(v);
            }
            *(uint2*)(hout + (size_t)n * F + w * 32 + g * 8 + hf * 4) = *(uint2*)o4;
        }
    } else {
        // h3 -> LDS only (C-layout: lane owns node n, dims w*32+g*8+hf*4+j)
        uint2 hv[4];
#pragma unroll
        for (int g = 0; g < 4; ++g) {
            ushort o4[4];
#pragma unroll
            for (int j = 0; j < 4; ++j) {
                float v = acc1[g * 4 + j] + acc2[g * 4 + j];
                v = v > 0.f ? v : 0.01f * v;
                o4[j] = (ushort)f2bf(v);
            }
            hv[g] = *(uint2*)o4;
        }
        __syncthreads();   // all mean-frag reads done
#pragma unroll
        for (int g = 0; g < 4; ++g)
            *(uint2*)&sM[l31 * 136 + w * 32 + g * 8 + hf * 4] = hv[g];

        bf16x8 afs[9], afd[8];
        const ushort* aps = aws + (size_t)(w * 32 + l31) * KS + hf * 8;
        const ushort* apd = awd + (size_t)(w * 32 + l31) * KD + hf * 8;
#pragma unroll
        for (int f = 0; f < 9; ++f) afs[f] = *(const bf16x8*)(aps + f * 16);
#pragma unroll
        for (int f = 0; f < 8; ++f) afd[f] = *(const bf16x8*)(apd + f * 16);
        __syncthreads();   // h3 tile visible

        f32x16 accS, accD;
#pragma unroll
        for (int r = 0; r < 16; ++r) { accS[r] = 0.f; accD[r] = 0.f; }
#pragma unroll
        for (int f = 0; f < 8; ++f) {
            bf16x8 b = *(const bf16x8*)&sM[l31 * 136 + hf * 8 + f * 16];
            accS = __builtin_amdgcn_mfma_f32_32x32x16_bf16(afs[f], b, accS, 0, 0, 0);
            accD = __builtin_amdgcn_mfma_f32_32x32x16_bf16(afd[f], b, accD, 0, 0, 0);
        }
        accS = __builtin_amdgcn_mfma_f32_32x32x16_bf16(afs[8], bx, accS, 0, 0, 0);

#pragma unroll
        for (int g = 0; g < 4; ++g) {
            half4 os, od;
#pragma unroll
            for (int j = 0; j < 4; ++j) {
                os[j] = (_Float16)accS[g * 4 + j];
                od[j] = (_Float16)accD[g * 4 + j];
            }
            int col = w * 32 + g * 8 + hf * 4;
            *(half4*)(zs + (size_t)n * F + col) = os;
            *(half4*)(zd + (size_t)n * F + col) = od;
        }
    }
}

// ---------------- final edge kernel (packed fp16 math) ----------------
__global__ __launch_bounds__(256) void edge_final(
    const _Float16* __restrict__ zs, const _Float16* __restrict__ zd,
    const float* __restrict__ ef,
    const int* __restrict__ src, const int* __restrict__ dst,
    const float* __restrict__ mw1, const float* __restrict__ mw2,
    const float* __restrict__ mb2, float* __restrict__ out) {
    int t = threadIdx.x;
    int g = t >> 4;       // edge slot 0..15
    int fl = t & 15;      // feature chunk

    half8 wf8;
    half2v w2a2[4], w2b2[4];
#pragma unroll
    for (int j = 0; j < 8; ++j) {
        int feat = fl * 8 + j;
        wf8[j] = (_Float16)mw1[(size_t)256 * 128 + feat];
    }
#pragma unroll
    for (int j = 0; j < 4; ++j) {
        int feat = fl * 8 + 2 * j;
        w2a2[j][0] = (_Float16)mw2[feat * 2];
        w2a2[j][1] = (_Float16)mw2[(feat + 1) * 2];
        w2b2[j][0] = (_Float16)mw2[feat * 2 + 1];
        w2b2[j][1] = (_Float16)mw2[(feat + 1) * 2 + 1];
    }
    float b20 = mb2[0], b21 = mb2[1];

    int e0 = blockIdx.x * (16 * EROUNDS);
    int isv[EROUNDS], idv[EROUNDS];
    float efv[EROUNDS];
#pragma unroll
    for (int r = 0; r < EROUNDS; ++r) {
        int e = e0 + r * 16 + g;
        isv[r] = src[e];
        idv[r] = dst[e];
        efv[r] = ef[e];
    }
#pragma unroll
    for (int r = 0; r < EROUNDS; ++r) {
        int e = e0 + r * 16 + g;
        half8 a = *(const half8*)(zs + (size_t)isv[r] * F + fl * 8);
        half8 b = *(const half8*)(zd + (size_t)idv[r] * F + fl * 8);
        _Float16 eh = (_Float16)efv[r];
        half8 e8 = {eh, eh, eh, eh, eh, eh, eh, eh};
        half8 v = a + b + wf8 * e8;                    // v_pk_add/fma_f16
        half8 zero = {0, 0, 0, 0, 0, 0, 0, 0};
        v = __builtin_elementwise_max(v, zero);        // v_pk_max_f16
        float p0 = 0.f, p1 = 0.f;
#if __has_builtin(__builtin_amdgcn_fdot2)
#pragma unroll
        for (int j = 0; j < 4; ++j) {
            half2v hv = {v[2 * j], v[2 * j + 1]};
            p0 = __builtin_amdgcn_fdot2(hv, w2a2[j], p0, false);
            p1 = __builtin_amdgcn_fdot2(hv, w2b2[j], p1, false);
        }
#else
#pragma unroll
        for (int j = 0; j < 4; ++j) {
            p0 += (float)v[2 * j] * (float)w2a2[j][0] + (float)v[2 * j + 1] * (float)w2a2[j][1];
            p1 += (float)v[2 * j] * (float)w2b2[j][0] + (float)v[2 * j + 1] * (float)w2b2[j][1];
        }
#endif
#pragma unroll
        for (int m = 1; m < 16; m <<= 1) {
            p0 += __shfl_xor(p0, m, 64);
            p1 += __shfl_xor(p1, m, 64);
        }
        if (fl == 0) *(float2*)&out[(size_t)e * 2] = make_float2(p0 + b20, p1 + b21);
    }
}

// ---------------- launch ----------------

extern "C" void kernel_launch(void* const* d_in, const int* in_sizes, int n_in,
                              void* d_out, int out_size, void* d_ws, size_t ws_size,
                              hipStream_t stream) {
    const float* node_feats = (const float*)d_in[0];
    const float* edge_feats = (const float*)d_in[1];
    const int*   src = (const int*)d_in[2];
    const int*   dst = (const int*)d_in[3];
    const float* ws0 = (const float*)d_in[4];
    const float* wn0 = (const float*)d_in[5];
    const float* b0  = (const float*)d_in[6];
    const float* ws1 = (const float*)d_in[7];
    const float* wn1 = (const float*)d_in[8];
    const float* b1  = (const float*)d_in[9];
    const float* ws2 = (const float*)d_in[10];
    const float* wn2 = (const float*)d_in[11];
    const float* b2  = (const float*)d_in[12];
    const float* mw1 = (const float*)d_in[13];
    const float* mb1 = (const float*)d_in[14];
    const float* mw2 = (const float*)d_in[15];
    const float* mb2 = (const float*)d_in[16];
    float* out = (float*)d_out;

    char* ws = (char*)d_ws;
    size_t off = 0;
    auto alloc = [&](size_t bytes) {
        size_t o = off;
        off += (bytes + 511) & ~(size_t)511;
        return o;
    };
    ushort* nfb = (ushort*)(ws + alloc((size_t)N_NODES * F * 2));
    ushort* hb0 = (ushort*)(ws + alloc((size_t)N_NODES * F * 2));
    ushort* hb1 = (ushort*)(ws + alloc((size_t)N_NODES * F * 2));
    ushort* zsb = (ushort*)(ws + alloc((size_t)N_NODES * F * 2));
    int*   deg  = (int*)  (ws + alloc((size_t)N_NODES * 4));
    float* invd = (float*)(ws + alloc((size_t)N_NODES * 4));
    int*   rowp = (int*)  (ws + alloc(((size_t)N_NODES + 1) * 4));
    int*   incl = (int*)  (ws + alloc((size_t)N_NODES * 4));
    int*   bsum = (int*)  (ws + alloc((size_t)NB * 4));
    int*   boff = (int*)  (ws + alloc((size_t)NB * 4));
    int*   csrc = (int*)  (ws + alloc((size_t)N_EDGES * 4));
    int*   bcur = (int*)  (ws + alloc((size_t)NBUCK * 4));
    unsigned* bstore = (unsigned*)(ws + alloc((size_t)NBUCK * BCAP * 4));
    ushort* aw0 = (ushort*)(ws + alloc((size_t)128 * KW * 2));
    ushort* aw1 = (ushort*)(ws + alloc((size_t)128 * KW * 2));
    ushort* aw2 = (ushort*)(ws + alloc((size_t)128 * KW * 2));
    ushort* awS = (ushort*)(ws + alloc((size_t)128 * KS * 2));
    ushort* awD = (ushort*)(ws + alloc((size_t)128 * KD * 2));
    // aliases (lifetimes disjoint): zs in zsb; zd reuses nfb (dead after layer 0... layer 1)
    _Float16* zs = (_Float16*)zsb;
    _Float16* zd = (_Float16*)nfb;

    // --- CSR build (bucketed, batched reservation) ---
    hipMemsetAsync(bcur, 0, (size_t)NBUCK * 4, stream);
    bucket_scatter<<<NSBLK, 256, 0, stream>>>(src, dst, bcur, bstore);
    bucket_deg<<<NBUCK, 256, 0, stream>>>(bstore, bcur, deg);
    scan1_kernel<<<NB, 1024, 0, stream>>>(deg, incl, bsum);
    scan2_kernel<<<1, 128, 0, stream>>>(bsum, boff, rowp);
    scan3_kernel<<<NB, 1024, 0, stream>>>(incl, deg, boff, rowp, invd);
    bucket_fill<<<NBUCK, 256, 0, stream>>>(bstore, bcur, rowp, csrc);

    // --- unified weight/feature prep ---
    prep_all<<<544 + N_NODES * F / 8 / 256, 256, 0, stream>>>(
        ws0, wn0, b0, ws1, wn1, b1, ws2, wn2, b2, mw1, mb1,
        aw0, aw1, aw2, awS, awD, node_feats, nfb);

    // --- 3 fused SAGE layers (layer 2 also emits zs/zd; h3 never hits HBM) ---
    agg_sage_fused<false><<<N_NODES / 32, 256, 0, stream>>>(
        nfb, csrc, rowp, invd, aw0, hb0, nullptr, nullptr, nullptr, nullptr);
    agg_sage_fused<false><<<N_NODES / 32, 256, 0, stream>>>(
        hb0, csrc, rowp, invd, aw1, hb1, nullptr, nullptr, nullptr, nullptr);
    agg_sage_fused<true><<<N_NODES / 32, 256, 0, stream>>>(
        hb1, csrc, rowp, invd, aw2, hb0, awS, awD, zs, zd);

    // --- edge MLP ---
    edge_final<<<N_EDGES / (16 * EROUNDS), 256, 0, stream>>>(
        zs, zd, edge_feats, src, dst, mw1, mw2, mb2, out);
}